// Round 8
// baseline (194.065 us; speedup 1.0000x reference)
//
#include <hip/hip_runtime.h>
#include <hip/hip_bf16.h>

#define NL    64
#define DIN   512
#define DOUT  512
#define BATCH 1024

#define BM 128
#define BN 128
#define BK 32
#define NK (DIN / BK)   // 16

typedef short short8 __attribute__((ext_vector_type(8)));
typedef float f32x4  __attribute__((ext_vector_type(4)));

__device__ __forceinline__ unsigned int pk2(float a, float b) {
    // v_cvt_pk_bf16_f32 (RNE)
    __hip_bfloat162 h = __float22bfloat162_rn(make_float2(a, b));
    unsigned int r;
    __builtin_memcpy(&r, &h, 4);
    return r;
}

__global__ __launch_bounds__(256, 3) void nlinear_kernel(
        const float* __restrict__ x, const float* __restrict__ w,
        const float* __restrict__ bias, float* __restrict__ out) {
    // ONLY B (w, transposed) in LDS: [col][k] bf16, 32-elem (64B) rows,
    // 16B-slot XOR swizzle: slot ^= (col & 3). Double-buffered: 2 x 8 KB.
    __shared__ unsigned short Bs[2][BN * BK];

    const int tid = threadIdx.x;
    const int bid = blockIdx.x;
    // XCD swizzle: 2048 = 8 XCDs x 256 blocks; each XCD owns 8 whole layers
    const int nb    = (bid & 7) * 256 + (bid >> 3);
    const int layer = nb >> 5;
    const int tile  = nb & 31;
    const int bm0   = (tile >> 2) * BM;
    const int bn0   = (tile & 3) * BN;

    const int wid  = tid >> 6;
    const int lane = tid & 63;
    const int wr   = wid >> 1, wc = wid & 1;   // 2x2 waves, 64x64 tile each
    const int lrow = lane & 15;
    const int lkb  = lane >> 4;                // k-octet 0..3

    // B-stage: gk = k-quad 0..7 (4 k each), gn = col-group 0..31 (4 cols each)
    const int gk = tid & 7;
    const int gn = tid >> 3;

    const size_t XS = (size_t)NL * DIN;        // x row stride (floats)
    const float* wb = w + (size_t)layer * DIN * DOUT + bn0;
    const float* bptr0 = wb + (size_t)(gk * 4) * DOUT + gn * 4;

    // Per-lane A row pointers (4 mi rows), k-offset lkb*8
    const float* arow[4];
#pragma unroll
    for (int mi = 0; mi < 4; ++mi)
        arow[mi] = x + (size_t)(bm0 + wr * 64 + mi * 16 + lrow) * XS
                     + (size_t)layer * DIN + lkb * 8;

    f32x4 acc[4][4];
#pragma unroll
    for (int i = 0; i < 4; ++i)
#pragma unroll
        for (int j = 0; j < 4; ++j) acc[i][j] = (f32x4){0.f, 0.f, 0.f, 0.f};

    f32x4 avp[4][2];   // A fp32 in flight (tile k)
    f32x4 bv[4];       // B fp32 in flight (tile k+1)

    auto loadA = [&](int kt) {
#pragma unroll
        for (int mi = 0; mi < 4; ++mi) {
            const float* p = arow[mi] + kt * BK;
            avp[mi][0] = *reinterpret_cast<const f32x4*>(p);
            avp[mi][1] = *reinterpret_cast<const f32x4*>(p + 4);
        }
    };
    auto loadB = [&](int kt) {
#pragma unroll
        for (int i = 0; i < 4; ++i)
            bv[i] = *reinterpret_cast<const f32x4*>(
                bptr0 + (size_t)(kt * BK + i) * DOUT);
    };
    auto cvtA = [&](short8* af) {
#pragma unroll
        for (int mi = 0; mi < 4; ++mi) {
            uint4 uv;
            uv.x = pk2(avp[mi][0][0], avp[mi][0][1]);
            uv.y = pk2(avp[mi][0][2], avp[mi][0][3]);
            uv.z = pk2(avp[mi][1][0], avp[mi][1][1]);
            uv.w = pk2(avp[mi][1][2], avp[mi][1][3]);
            __builtin_memcpy(&af[mi], &uv, 16);
        }
    };
    auto cvtwriteB = [&](int b) {
#pragma unroll
        for (int j = 0; j < 4; ++j) {
            const int c = gn * 4 + j;
            uint2 wv;
            wv.x = pk2(bv[0][j], bv[1][j]);
            wv.y = pk2(bv[2][j], bv[3][j]);
            const int off = c * BK + (((gk >> 1) ^ (c & 3)) << 3) + ((gk & 1) << 2);
            *reinterpret_cast<uint2*>(&Bs[b][off]) = wv;
        }
    };
    auto fragB = [&](int b, short8* bf) {
#pragma unroll
        for (int ni = 0; ni < 4; ++ni) {
            const int col = wc * 64 + ni * 16 + lrow;
            bf[ni] = *reinterpret_cast<const short8*>(
                &Bs[b][col * BK + ((lkb ^ (col & 3)) << 3)]);
        }
    };

#define BARRIER() do { \
        asm volatile("s_waitcnt lgkmcnt(0)" ::: "memory"); \
        __builtin_amdgcn_sched_barrier(0); \
        __builtin_amdgcn_s_barrier(); \
        __builtin_amdgcn_sched_barrier(0); } while (0)

#define MFMA16(AF, BF) do { \
        __builtin_amdgcn_s_setprio(1); \
        _Pragma("unroll") \
        for (int mi = 0; mi < 4; ++mi) \
        _Pragma("unroll") \
            for (int ni = 0; ni < 4; ++ni) \
                acc[mi][ni] = __builtin_amdgcn_mfma_f32_16x16x32_bf16( \
                    AF[mi], BF[ni], acc[mi][ni], 0, 0, 0); \
        __builtin_amdgcn_s_setprio(0); } while (0)

    // ---- prologue: B(0) staged, B(1) + A(0) in flight ----
    loadB(0);
    loadA(0);
    cvtwriteB(0);      // waits vmcnt on B(0) only
    loadB(1);
    BARRIER();

    // ---- steady state: 1 no-drain barrier per K-step ----
#pragma unroll 1
    for (int k = 0; k < NK - 2; ++k) {
        short8 af[4], bf[4];
        fragB(k & 1, bf);          // ds_read, no vmem dep
        cvtwriteB((k + 1) & 1);    // vmcnt(B k+1): 1 full iter in flight
        loadB(k + 2);
        cvtA(af);                  // vmcnt(A k): 1 full iter in flight
        loadA(k + 1);
        MFMA16(af, bf);            // lgkm wait on bf
        BARRIER();
    }
    // ---- k = NK-2: last B restage, last A load ----
    {
        short8 af[4], bf[4];
        fragB((NK - 2) & 1, bf);
        cvtwriteB((NK - 1) & 1);
        cvtA(af);
        loadA(NK - 1);
        MFMA16(af, bf);
        BARRIER();
    }
    // ---- k = NK-1: compute only ----
    {
        short8 af[4], bf[4];
        fragB((NK - 1) & 1, bf);
        cvtA(af);
        MFMA16(af, bf);
    }

    // ---- epilogue: + bias, fp32 store ----
    const float* bb = bias + (size_t)layer * DOUT + bn0;
    float* ob = out + (size_t)bm0 * (NL * DOUT) + (size_t)layer * DOUT + bn0;
#pragma unroll
    for (int mi = 0; mi < 4; ++mi) {
#pragma unroll
        for (int ni = 0; ni < 4; ++ni) {
            const int col = wc * 64 + ni * 16 + lrow;
            const float bval = bb[col];
#pragma unroll
            for (int r = 0; r < 4; ++r) {
                const int row = wr * 64 + mi * 16 + lkb * 4 + r;
                ob[(size_t)row * (NL * DOUT) + col] = acc[mi][ni][r] + bval;
            }
        }
    }
#undef BARRIER
#undef MFMA16
}

extern "C" void kernel_launch(void* const* d_in, const int* in_sizes, int n_in,
                              void* d_out, int out_size, void* d_ws, size_t ws_size,
                              hipStream_t stream) {
    const float* x  = (const float*)d_in[0];
    const float* w  = (const float*)d_in[1];
    const float* b  = (const float*)d_in[2];
    float* out      = (float*)d_out;

    dim3 grid(NL * (BATCH / BM) * (DOUT / BN));   // 2048
    dim3 block(256);
    hipLaunchKernelGGL(nlinear_kernel, grid, block, 0, stream, x, w, b, out);
}

// Round 9
// 93.178 us; speedup vs baseline: 2.0827x; 2.0827x over previous
//
#include <hip/hip_runtime.h>
#include <hip/hip_bf16.h>

#define NL    64
#define DIN   512
#define DOUT  512
#define BATCH 1024

#define BM 256
#define BN 256
#define BK 32
#define NK (DIN / BK)   // 16
#define LDS_STRIDE 40   // 32 + 8 pad (80 B rows)

typedef short short8 __attribute__((ext_vector_type(8)));
typedef float f32x4  __attribute__((ext_vector_type(4)));

__device__ __forceinline__ unsigned int pk2(float a, float b) {
    // v_cvt_pk_bf16_f32 (RNE)
    __hip_bfloat162 h = __float22bfloat162_rn(make_float2(a, b));
    unsigned int r;
    __builtin_memcpy(&r, &h, 4);
    return r;
}

__global__ __launch_bounds__(512, 2) void nlinear_kernel(
        const float* __restrict__ x, const float* __restrict__ w,
        const float* __restrict__ bias, float* __restrict__ out) {
    // Double-buffered bf16 tiles [row][k], padded stride 40 (no XOR swizzle).
    __shared__ unsigned short As[2][BM * LDS_STRIDE];   // 2 x 20 KB
    __shared__ unsigned short Bs[2][BN * LDS_STRIDE];   // 2 x 20 KB

    const int tid = threadIdx.x;
    const int bid = blockIdx.x;
    // XCD swizzle: 512 blocks = 8 XCDs x 64; each XCD owns 8 whole layers.
    // Tile order n-major: 4 consecutive m-tiles share one w n-slice.
    const int nb    = (bid & 7) * 64 + (bid >> 3);
    const int layer = nb >> 3;
    const int t     = nb & 7;
    const int bm0   = (t & 3) * BM;     // 4 m-tiles
    const int bn0   = (t >> 2) * BN;    // 2 n-tiles

    const int wid  = tid >> 6;
    const int lane = tid & 63;
    const int wr   = wid >> 2, wc = wid & 3;   // 2x4 waves, each 128x64
    const int lrow = lane & 15;
    const int lkb  = lane >> 4;                // k-octet 0..3

    // A-stage: 8 lanes/row (full 128B row), rows ar+64p, p=0..3
    const int ar = tid >> 3;            // 0..63
    const int ak = tid & 7;             // f32x4 slot in row
    // B-stage: wave gw owns k-quad gw (4 consecutive k), lane gc owns col-quad
    const int gw = tid >> 6;            // 0..7
    const int gc = tid & 63;            // 0..63

    const size_t XS = (size_t)NL * DIN;        // x row stride (floats)
    const float* xb = x + (size_t)bm0 * XS + (size_t)layer * DIN;
    const float* wb = w + (size_t)layer * DIN * DOUT + bn0;
    const float* aptr0 = xb + (size_t)ar * XS + ak * 4;
    const float* bptr0 = wb + (size_t)(gw * 4) * DOUT + gc * 4;

    f32x4 acc[8][4];
#pragma unroll
    for (int i = 0; i < 8; ++i)
#pragma unroll
        for (int j = 0; j < 4; ++j) acc[i][j] = (f32x4){0.f, 0.f, 0.f, 0.f};

    f32x4 av[4], bv[4];

    auto issue = [&](int kt) {
        // A: per instr, 8 rows x 128B contiguous (8 dense transactions)
#pragma unroll
        for (int p = 0; p < 4; ++p)
            av[p] = *reinterpret_cast<const f32x4*>(
                aptr0 + (size_t)(64 * p) * XS + kt * BK);
        // B: per instr, 64 lanes x 16B = 1KB contiguous (perfect coalescing)
#pragma unroll
        for (int p = 0; p < 4; ++p)
            bv[p] = *reinterpret_cast<const f32x4*>(
                bptr0 + (size_t)(kt * BK + p) * DOUT);
    };

    auto cvtwrite = [&](int b) {
        // A: 4x ds_write_b64, row ar+64p, k-slot ak
#pragma unroll
        for (int p = 0; p < 4; ++p) {
            uint2 wv;
            wv.x = pk2(av[p][0], av[p][1]);
            wv.y = pk2(av[p][2], av[p][3]);
            *reinterpret_cast<uint2*>(
                &As[b][(ar + 64 * p) * LDS_STRIDE + ak * 4]) = wv;
        }
        // B transpose: 4x ds_write_b64, col gc*4+j, k-quad gw (consecutive k!)
#pragma unroll
        for (int j = 0; j < 4; ++j) {
            const int col = gc * 4 + j;
            uint2 wv;
            wv.x = pk2(bv[0][j], bv[1][j]);
            wv.y = pk2(bv[2][j], bv[3][j]);
            *reinterpret_cast<uint2*>(
                &Bs[b][col * LDS_STRIDE + gw * 4]) = wv;
        }
    };

    auto fragA = [&](int b, short8* af) {
#pragma unroll
        for (int mi = 0; mi < 8; ++mi) {
            const int row = wr * 128 + mi * 16 + lrow;
            af[mi] = *reinterpret_cast<const short8*>(
                &As[b][row * LDS_STRIDE + lkb * 8]);
        }
    };
    auto fragB = [&](int b, short8* bf) {
#pragma unroll
        for (int ni = 0; ni < 4; ++ni) {
            const int col = wc * 64 + ni * 16 + lrow;
            bf[ni] = *reinterpret_cast<const short8*>(
                &Bs[b][col * LDS_STRIDE + lkb * 8]);
        }
    };

#define BARRIER() do { \
        asm volatile("s_waitcnt lgkmcnt(0)" ::: "memory"); \
        __builtin_amdgcn_sched_barrier(0); \
        __builtin_amdgcn_s_barrier(); \
        __builtin_amdgcn_sched_barrier(0); } while (0)

#define MFMA32(AF, BF) do { \
        __builtin_amdgcn_s_setprio(1); \
        _Pragma("unroll") \
        for (int mi = 0; mi < 8; ++mi) \
        _Pragma("unroll") \
            for (int ni = 0; ni < 4; ++ni) \
                acc[mi][ni] = __builtin_amdgcn_mfma_f32_16x16x32_bf16( \
                    AF[mi], BF[ni], acc[mi][ni], 0, 0, 0); \
        __builtin_amdgcn_s_setprio(0); } while (0)

    // ---- prologue: tile0 -> buf0, tile1 loads in flight ----
    issue(0);
    cvtwrite(0);
    issue(1);
    BARRIER();

    // ---- steady state: 1 no-drain barrier per K-step ----
#pragma unroll 1
    for (int k = 0; k < NK - 2; ++k) {
        short8 af[8], bf[4];
        fragA(k & 1, af);          // ds_reads, no vmem dep
        fragB(k & 1, bf);
        cvtwrite((k + 1) & 1);     // vmcnt on tile k+1 (1 K-step in flight)
        issue(k + 2);              // next loads fly under MFMA
        MFMA32(af, bf);
        BARRIER();
    }
    // ---- k = NK-2: last restage ----
    {
        short8 af[8], bf[4];
        fragA((NK - 2) & 1, af);
        fragB((NK - 2) & 1, bf);
        cvtwrite((NK - 1) & 1);
        MFMA32(af, bf);
        BARRIER();
    }
    // ---- k = NK-1: compute only ----
    {
        short8 af[8], bf[4];
        fragA((NK - 1) & 1, af);
        fragB((NK - 1) & 1, bf);
        MFMA32(af, bf);
    }

    // ---- epilogue: + bias, fp32 store ----
    const float* bb = bias + (size_t)layer * DOUT + bn0;
    float* ob = out + (size_t)bm0 * (NL * DOUT) + (size_t)layer * DOUT + bn0;
#pragma unroll
    for (int mi = 0; mi < 8; ++mi) {
#pragma unroll
        for (int ni = 0; ni < 4; ++ni) {
            const int col = wc * 64 + ni * 16 + lrow;
            const float bval = bb[col];
#pragma unroll
            for (int r = 0; r < 4; ++r) {
                const int row = wr * 128 + mi * 16 + lkb * 4 + r;
                ob[(size_t)row * (NL * DOUT) + col] = acc[mi][ni][r] + bval;
            }
        }
    }
#undef BARRIER
#undef MFMA32
}

extern "C" void kernel_launch(void* const* d_in, const int* in_sizes, int n_in,
                              void* d_out, int out_size, void* d_ws, size_t ws_size,
                              hipStream_t stream) {
    const float* x  = (const float*)d_in[0];
    const float* w  = (const float*)d_in[1];
    const float* b  = (const float*)d_in[2];
    float* out      = (float*)d_out;

    dim3 grid(NL * (BATCH / BM) * (DOUT / BN));   // 64 * 4 * 2 = 512
    dim3 block(512);
    hipLaunchKernelGGL(nlinear_kernel, grid, block, 0, stream, x, w, b, out);
}